// Round 9
// baseline (1409.764 us; speedup 1.0000x reference)
//
#include <hip/hip_runtime.h>
#include <hip/hip_bf16.h>

// Problem constants
#define Bz 16
#define Tz 32
#define Sz 128
#define TPz 4
#define Mz (Bz*Sz)          // 2048 rows
#define NSTEP (Tz-1)        // 31

typedef __bf16 bf16x8 __attribute__((ext_vector_type(8)));
typedef float  f32x4  __attribute__((ext_vector_type(4)));

#define MFMA __builtin_amdgcn_mfma_f32_16x16x32_bf16

__device__ __forceinline__ float sigf(float x) { return 1.f/(1.f + __expf(-x)); }

// ---------------------------------------------------------------------------
// prep4: qkv weights row-major K-major (for the LDS-staged D1 GEMM, round-6
// verified) + gate/emb weights in MFMA B-fragment order (round-7/8 verified):
//   P[((nt*KT + kt)*64 + lane)*8 + j] = BT[nt*16 + (lane&15)][kt*32 + (lane>>4)*8 + j]
//  Wqkv_e [768][256] row-major : enc [Wq|Wk|Wv]^T
//  Wqkv_d [768][256] row-major : dec [Wq|Wk|Wv]^T
//  Pemb   frag (16 nt x 8 kt)  : embW^T
//  Pg_e   frag (64 nt x 16 kt) : enc gates, nt=cht*4+g, ch=cht*16+(lane&15); K=[h|ctx]
//  Pg_d   frag (64 nt x 24 kt) : dec gates, K=[code|dh|ctx]
// ---------------------------------------------------------------------------
__global__ __launch_bounds__(256) void prep4(
    const float* __restrict__ encWq, const float* __restrict__ encWk,
    const float* __restrict__ encWv, const float* __restrict__ encWg,
    const float* __restrict__ decWq, const float* __restrict__ decWk,
    const float* __restrict__ decWv, const float* __restrict__ decWg,
    const float* __restrict__ embW,
    __bf16* __restrict__ Wqkv_e, __bf16* __restrict__ Wqkv_d,
    __bf16* __restrict__ Pemb,   __bf16* __restrict__ Pg_e,
    __bf16* __restrict__ Pg_d)
{
    int id = blockIdx.x * 256 + threadIdx.x;
    if (id < 768*256) {
        int n = id >> 8, k = id & 255;
        float v = (n < 256) ? encWq[k*256 + n]
                : (n < 512) ? encWk[k*256 + (n-256)]
                            : encWv[k*256 + (n-512)];
        Wqkv_e[id] = (__bf16)v; return;
    }
    id -= 768*256;
    if (id < 768*256) {
        int n = id >> 8, k = id & 255;
        float v = (n < 256) ? decWq[k*256 + n]
                : (n < 512) ? decWk[k*256 + (n-256)]
                            : decWv[k*256 + (n-512)];
        Wqkv_d[id] = (__bf16)v; return;
    }
    id -= 768*256;
    if (id < 256*256) {
        int f = id >> 9, e = id & 511, l = e >> 3, j = e & 7;
        int nt = f >> 3, kt = f & 7;
        int n = nt*16 + (l & 15), k = kt*32 + (l >> 4)*8 + j;
        Pemb[id] = (__bf16)embW[k*256 + n]; return;
    }
    id -= 256*256;
    if (id < 1024*512) {
        int f = id >> 9, e = id & 511, l = e >> 3, j = e & 7;
        int nt = f >> 4, kt = f & 15;
        int cht = nt >> 2, g = nt & 3;
        int ch = cht*16 + (l & 15), k = kt*32 + (l >> 4)*8 + j;
        Pg_e[id] = (__bf16)encWg[(size_t)(3 + k)*1024 + g*256 + ch]; return;
    }
    id -= 1024*512;
    if (id < 1024*768) {
        int f = id >> 9, e = id & 511, l = e >> 3, j = e & 7;
        int nt = f / 24, kt = f % 24;
        int cht = nt >> 2, g = nt & 3;
        int ch = cht*16 + (l & 15), k = kt*32 + (l >> 4)*8 + j;
        Pg_d[id] = (__bf16)decWg[(size_t)k*1024 + g*256 + ch]; return;
    }
}

// ---------------------------------------------------------------------------
// D1: combo qkv GEMM (round-6 verified 128x128 core, K=256, lda=512).
// y<6: enc (A=Xp[,0:256], B=Wqkv_e) -> q_e / kv_e
// y>=6: dec (A=Xp[,256:512], B=Wqkv_d) -> q_d / kv_d
// ---------------------------------------------------------------------------
__global__ __launch_bounds__(256, 2) void gemm_qkv2(
    const __bf16* __restrict__ Xp,
    const __bf16* __restrict__ We, const __bf16* __restrict__ Wd,
    __bf16* __restrict__ q_e, __bf16* __restrict__ kv_e,
    __bf16* __restrict__ q_d, __bf16* __restrict__ kv_d)
{
    __shared__ __attribute__((aligned(16))) __bf16 As[128*32];
    __shared__ __attribute__((aligned(16))) __bf16 Bs[128*32];
    const int tid  = threadIdx.x;
    const bool dec = blockIdx.y >= 6;
    const int m0   = blockIdx.x << 7;
    const int n0   = (dec ? (blockIdx.y - 6) : blockIdx.y) << 7;
    const int lane = tid & 63;
    const int w    = tid >> 6;
    const int quad = lane >> 4, lr = lane & 15;
    const int wm   = (w >> 1) << 6, wn = (w & 1) << 6;

    const __bf16* A  = Xp + (dec ? 256 : 0);
    const __bf16* BT = dec ? Wd : We;
    __bf16* qo  = dec ? q_d  : q_e;
    __bf16* kvo = dec ? kv_d : kv_e;

    f32x4 acc[4][4];
    #pragma unroll
    for (int i = 0; i < 4; ++i)
        #pragma unroll
        for (int j = 0; j < 4; ++j) acc[i][j] = f32x4{0.f,0.f,0.f,0.f};

    const int r0 = tid >> 2;
    const int c0 = (tid & 3) << 3;
    const __bf16* gA0 = A  + (size_t)(m0 + r0)      * 512 + c0;
    const __bf16* gA1 = A  + (size_t)(m0 + r0 + 64) * 512 + c0;
    const __bf16* gB0 = BT + (size_t)(n0 + r0)      * 256 + c0;
    const __bf16* gB1 = BT + (size_t)(n0 + r0 + 64) * 256 + c0;

    for (int k0 = 0; k0 < 256; k0 += 32) {
        uint4 a0 = *(const uint4*)(gA0 + k0);
        uint4 a1 = *(const uint4*)(gA1 + k0);
        uint4 b0 = *(const uint4*)(gB0 + k0);
        uint4 b1 = *(const uint4*)(gB1 + k0);
        __syncthreads();
        ((uint4*)As)[tid]       = a0;
        ((uint4*)As)[tid + 256] = a1;
        ((uint4*)Bs)[tid]       = b0;
        ((uint4*)Bs)[tid + 256] = b1;
        __syncthreads();
        bf16x8 af[4], bfr[4];
        #pragma unroll
        for (int i = 0; i < 4; ++i)
            af[i]  = *(const bf16x8*)&As[(wm + i*16 + lr)*32 + quad*8];
        #pragma unroll
        for (int i = 0; i < 4; ++i)
            bfr[i] = *(const bf16x8*)&Bs[(wn + i*16 + lr)*32 + quad*8];
        #pragma unroll
        for (int mi = 0; mi < 4; ++mi)
            #pragma unroll
            for (int ni = 0; ni < 4; ++ni)
                acc[mi][ni] = MFMA(af[mi], bfr[ni], acc[mi][ni], 0, 0, 0);
    }

    #pragma unroll
    for (int mi = 0; mi < 4; ++mi) {
        #pragma unroll
        for (int ni = 0; ni < 4; ++ni) {
            const int col = n0 + wn + ni*16 + lr;
            #pragma unroll
            for (int r = 0; r < 4; ++r) {
                const int row = m0 + wm + mi*16 + quad*4 + r;
                float v = acc[mi][ni][r];
                if (col < 256) qo[(size_t)row*256 + col] = (__bf16)v;
                else           kvo[(size_t)row*512 + (col-256)] = (__bf16)v;
            }
        }
    }
}

// ---------------------------------------------------------------------------
// Attention for 32 rows from global q/kv (round-5/6 verified). ctx -> ctxL/264.
// ---------------------------------------------------------------------------
__device__ __forceinline__ void attn_dev32(
    const __bf16* __restrict__ q_g, const __bf16* __restrict__ kv_g,
    int gbatch, int s0r, int tid, __bf16* __restrict__ ctxL)
{
    const int w = tid >> 6, lane = tid & 63, quad = lane >> 4, lr = lane & 15;
    const int r = 4*w + quad;
    const int s = s0r + r;
    const int ch0 = lr*16;

    float q[16];
    {
        const bf16x8* qp = (const bf16x8*)(q_g + (size_t)(gbatch + s)*256 + ch0);
        bf16x8 q0 = qp[0], q1 = qp[1];
        #pragma unroll
        for (int i = 0; i < 8; ++i) { q[i] = (float)q0[i]; q[8+i] = (float)q1[i]; }
    }
    bf16x8 zv;
    #pragma unroll
    for (int i = 0; i < 8; ++i) zv[i] = (__bf16)0.f;

    const int offs[4] = {2, 1, -1, -2};
    float sc[4]; bf16x8 v0[4], v1[4];
    #pragma unroll
    for (int n = 0; n < 4; ++n) {
        int s2 = s + offs[n];
        bool ok = ((unsigned)s2 < 128u);
        float p = 0.f;
        if (ok) {
            const bf16x8* kp = (const bf16x8*)(kv_g + (size_t)(gbatch + s2)*512 + ch0);
            bf16x8 k0 = kp[0], k1 = kp[1];
            const bf16x8* vp = (const bf16x8*)(kv_g + (size_t)(gbatch + s2)*512 + 256 + ch0);
            v0[n] = vp[0]; v1[n] = vp[1];
            #pragma unroll
            for (int i = 0; i < 8; ++i) p += q[i]*(float)k0[i] + q[8+i]*(float)k1[i];
        } else { v0[n] = zv; v1[n] = zv; }
        p += __shfl_xor(p, 1);
        sc[n] = ok ? p * 0.17677669529663687f : 0.f;
    }
    float mx = fmaxf(fmaxf(sc[0], sc[1]), fmaxf(sc[2], sc[3]));
    float se = 0.f, aw[4];
    #pragma unroll
    for (int n = 0; n < 4; ++n) { aw[n] = __expf(sc[n] - mx); se += aw[n]; }
    float inv = 1.f/se;
    float cx[16];
    #pragma unroll
    for (int i = 0; i < 16; ++i) cx[i] = 0.f;
    #pragma unroll
    for (int n = 0; n < 4; ++n)
        #pragma unroll
        for (int i = 0; i < 8; ++i) {
            cx[i]   += aw[n]*(float)v0[n][i];
            cx[8+i] += aw[n]*(float)v1[n][i];
        }
    bf16x8 o0, o1;
    #pragma unroll
    for (int i = 0; i < 8; ++i) { o0[i] = (__bf16)(cx[i]*inv); o1[i] = (__bf16)(cx[8+i]*inv); }
    *(bf16x8*)&ctxL[r*264 + ch0]     = o0;
    *(bf16x8*)&ctxL[r*264 + ch0 + 8] = o1;
}

// ---------------------------------------------------------------------------
// F_enc: 256 blocks = (b, rg, qt), 512 threads, 2 blocks/CU.
// Stage h own rows; attn (global q/kv); gates K=512 frag-B; LSTM -> ec, Xq.
// ---------------------------------------------------------------------------
__global__ __launch_bounds__(512, 2) void f_enc(
    const float* __restrict__ input, int t,
    const __bf16* __restrict__ Xp, __bf16* __restrict__ Xq,
    const __bf16* __restrict__ q_e, const __bf16* __restrict__ kv_e,
    const __bf16* __restrict__ Pg_e,
    const float* __restrict__ encWg, const float* __restrict__ encbg,
    float* __restrict__ ec)
{
    __shared__ __attribute__((aligned(16))) __bf16 hL [32*264];
    __shared__ __attribute__((aligned(16))) __bf16 cxL[32*264];
    __shared__ float xL[96];

    const int tid  = threadIdx.x;
    const int w    = tid >> 6;
    const int lane = tid & 63;
    const int quad = lane >> 4, lr = lane & 15;
    const int b    = blockIdx.x >> 4;
    const int rg   = (blockIdx.x >> 2) & 3;
    const int qt   = blockIdx.x & 3;
    const int gbatch = b*128, s0 = rg*32, grow0 = gbatch + s0;
    const int mt = w >> 2, ct = w & 3;
    const int ch = qt*64 + ct*16 + lr;

    // stage ehb_{t-1} own rows
    #pragma unroll
    for (int it = 0; it < 2; ++it) {
        const int v = tid*2 + it, row = v >> 5, seg = v & 31;
        *(bf16x8*)&hL[row*264 + seg*8] =
            *(const bf16x8*)&Xp[(size_t)(grow0 + row)*512 + seg*8];
    }
    if (tid < 96) xL[tid] = input[((size_t)(b*Tz + t)*Sz + s0)*3 + tid];

    attn_dev32(q_e, kv_e, gbatch, s0, tid, cxL);
    __syncthreads();

    // gates (K=512: hL | cxL), B from packed fragments
    float wx0[4], wx1[4], wx2[4], bgv[4];
    #pragma unroll
    for (int g = 0; g < 4; ++g) {
        const int c = g*256 + ch;
        wx0[g] = encWg[c]; wx1[g] = encWg[1024 + c]; wx2[g] = encWg[2048 + c];
        bgv[g] = encbg[c];
    }
    f32x4 acc[4];
    #pragma unroll
    for (int g = 0; g < 4; ++g) acc[g] = f32x4{0.f,0.f,0.f,0.f};
    for (int kt = 0; kt < 16; ++kt) {
        const __bf16* As = (kt < 8)
            ? &hL [(mt*16 + lr)*264 + kt*32 + quad*8]
            : &cxL[(mt*16 + lr)*264 + (kt-8)*32 + quad*8];
        bf16x8 af = *(const bf16x8*)As;
        #pragma unroll
        for (int g = 0; g < 4; ++g) {
            const int nt = qt*16 + ct*4 + g;
            bf16x8 bf = *(const bf16x8*)&Pg_e[((size_t)(nt*16 + kt)*64 + lane)*8];
            acc[g] = MFMA(af, bf, acc[g], 0,0,0);
        }
    }
    #pragma unroll
    for (int r = 0; r < 4; ++r) {
        const int row = mt*16 + quad*4 + r;
        const float x0 = xL[row*3], x1 = xL[row*3+1], x2 = xL[row*3+2];
        const float zi = acc[0][r] + x0*wx0[0] + x1*wx1[0] + x2*wx2[0] + bgv[0];
        const float zf = acc[1][r] + x0*wx0[1] + x1*wx1[1] + x2*wx2[1] + bgv[1];
        const float zg = acc[2][r] + x0*wx0[2] + x1*wx1[2] + x2*wx2[2] + bgv[2];
        const float zo = acc[3][r] + x0*wx0[3] + x1*wx1[3] + x2*wx2[3] + bgv[3];
        const size_t ei = (size_t)(grow0 + row)*256 + ch;
        const float cn = sigf(zf)*ec[ei] + sigf(zi)*tanhf(zg);
        ec[ei] = cn;
        Xq[(size_t)(grow0 + row)*512 + ch] = (__bf16)(sigf(zo)*tanhf(cn));
    }
}

// ---------------------------------------------------------------------------
// F_dec: 256 blocks = (b, rg, qt), 512 threads, 2 blocks/CU.
// Stage ehb_t + dh own rows; attn (global q_d/kv_d); code GEMM; gates K=768;
// LSTM + outproj -> Xq dec half, outbuf (atomicAdd partial).
// ---------------------------------------------------------------------------
__global__ __launch_bounds__(512, 2) void f_dec(
    const __bf16* __restrict__ Xp, __bf16* __restrict__ Xq,
    const __bf16* __restrict__ q_d, const __bf16* __restrict__ kv_d,
    const __bf16* __restrict__ Pemb, const __bf16* __restrict__ Pg_d,
    const float* __restrict__ embb, const float* __restrict__ decbg,
    const float* __restrict__ outW, float* __restrict__ outbuf)
{
    __shared__ __attribute__((aligned(16))) __bf16 ehtL [32*264];
    __shared__ __attribute__((aligned(16))) __bf16 dhL  [32*264];
    __shared__ __attribute__((aligned(16))) __bf16 codeL[32*264];
    __shared__ __attribute__((aligned(16))) __bf16 cxL  [32*264];
    __shared__ float outredL[128];

    const int tid  = threadIdx.x;
    const int w    = tid >> 6;
    const int lane = tid & 63;
    const int quad = lane >> 4, lr = lane & 15;
    const int b    = blockIdx.x >> 4;
    const int rg   = (blockIdx.x >> 2) & 3;
    const int qt   = blockIdx.x & 3;
    const int gbatch = b*128, s0 = rg*32, grow0 = gbatch + s0;
    const int mt = w >> 2, ct = w & 3;
    const int ch = qt*64 + ct*16 + lr;

    // stage ehb_t (enc half of Xq, written by f_enc this step) + dh_{t-1}
    #pragma unroll
    for (int it = 0; it < 2; ++it) {
        const int v = tid*2 + it, row = v >> 5, seg = v & 31;
        *(bf16x8*)&ehtL[row*264 + seg*8] =
            *(const bf16x8*)&Xq[(size_t)(grow0 + row)*512 + seg*8];
        *(bf16x8*)&dhL[row*264 + seg*8] =
            *(const bf16x8*)&Xp[(size_t)(grow0 + row)*512 + 256 + seg*8];
    }

    attn_dev32(q_d, kv_d, gbatch, s0, tid, cxL);
    __syncthreads();

    // code = sig(ehb_t @ embW + embb) -> codeL
    {
        f32x4 cacc[2][2];
        #pragma unroll
        for (int m = 0; m < 2; ++m)
            #pragma unroll
            for (int i = 0; i < 2; ++i) cacc[m][i] = f32x4{0.f,0.f,0.f,0.f};
        for (int kt = 0; kt < 8; ++kt) {
            bf16x8 a0 = *(const bf16x8*)&ehtL[(lr)*264      + kt*32 + quad*8];
            bf16x8 a1 = *(const bf16x8*)&ehtL[(16 + lr)*264 + kt*32 + quad*8];
            #pragma unroll
            for (int i = 0; i < 2; ++i) {
                bf16x8 bf = *(const bf16x8*)&Pemb[((size_t)((2*w + i)*8 + kt)*64 + lane)*8];
                cacc[0][i] = MFMA(a0, bf, cacc[0][i], 0,0,0);
                cacc[1][i] = MFMA(a1, bf, cacc[1][i], 0,0,0);
            }
        }
        #pragma unroll
        for (int i = 0; i < 2; ++i) {
            const int col = (2*w + i)*16 + lr;
            const float bb = embb[col];
            #pragma unroll
            for (int m = 0; m < 2; ++m)
                #pragma unroll
                for (int r = 0; r < 4; ++r)
                    codeL[(m*16 + quad*4 + r)*264 + col] = (__bf16)sigf(cacc[m][i][r] + bb);
        }
    }
    __syncthreads();

    // gates (K=768: codeL | dhL | cxL) + LSTM + outproj
    float bgv[4];
    #pragma unroll
    for (int g = 0; g < 4; ++g) bgv[g] = decbg[g*256 + ch];
    const float ow = outW[ch];

    f32x4 acc[4];
    #pragma unroll
    for (int g = 0; g < 4; ++g) acc[g] = f32x4{0.f,0.f,0.f,0.f};
    for (int kt = 0; kt < 24; ++kt) {
        const __bf16* As = (kt < 8)
            ? &codeL[(mt*16 + lr)*264 + kt*32 + quad*8]
            : (kt < 16)
            ? &dhL[(mt*16 + lr)*264 + (kt-8)*32 + quad*8]
            : &cxL[(mt*16 + lr)*264 + (kt-16)*32 + quad*8];
        bf16x8 af = *(const bf16x8*)As;
        #pragma unroll
        for (int g = 0; g < 4; ++g) {
            const int nt = qt*16 + ct*4 + g;
            bf16x8 bf = *(const bf16x8*)&Pg_d[((size_t)(nt*24 + kt)*64 + lane)*8];
            acc[g] = MFMA(af, bf, acc[g], 0,0,0);
        }
    }
    #pragma unroll
    for (int r = 0; r < 4; ++r) {
        const int row = mt*16 + quad*4 + r;
        const float zi = acc[0][r] + bgv[0];
        const float zf = acc[1][r] + bgv[1];
        const float zg = acc[2][r] + bgv[2];
        const float zo = acc[3][r] + bgv[3];
        const float c_old = (float)dhL[row*264 + ch];
        const float cn = sigf(zf)*c_old + sigf(zi)*tanhf(zg);
        const float h  = sigf(zo)*tanhf(cn);
        Xq[(size_t)(grow0 + row)*512 + 256 + ch] = (__bf16)h;
        float pv = h * ow;
        pv += __shfl_xor(pv, 1); pv += __shfl_xor(pv, 2);
        pv += __shfl_xor(pv, 4); pv += __shfl_xor(pv, 8);
        if (lr == 0) outredL[row*4 + ct] = pv;
    }
    __syncthreads();
    if (tid < 32) {
        const float s4 = outredL[tid*4] + outredL[tid*4+1]
                       + outredL[tid*4+2] + outredL[tid*4+3];
        atomicAdd(&outbuf[grow0 + tid], s4);
    }
}

// ---------------------------------------------------------------------------
// Final assembly (unchanged, verified)
// ---------------------------------------------------------------------------
__global__ __launch_bounds__(256) void assemble_k(
    const float* __restrict__ outbuf, const float* __restrict__ input,
    const float* __restrict__ outb, float* __restrict__ out)
{
    const int idx = blockIdx.x*256 + threadIdx.x;
    const int NT = NSTEP - TPz;                 // 27
    if (idx >= Bz*NT*Sz) return;
    const int s  = idx & 127;
    const int bi = idx >> 7;
    const int i  = bi % NT;
    const int b  = bi / NT;
    const int t  = i + TPz;
    const float ob = outb[0];
    const float o  = outbuf[t*Mz + (b<<7) + s] + ob;
    const float In = (s == 0)
        ? input[((size_t)(b*Tz + t + 1)*Sz)*3 + 1]
        : outbuf[t*Mz + (b<<7) + s - 1] + ob;
    const float num = input[((size_t)(b*Tz + t)*Sz + s)*3 + 2] + In - o;
    const size_t base = ((size_t)(b*NT + i)*Sz + s)*3;
    out[base+0] = o;
    out[base+1] = In;
    out[base+2] = num;
}

// ---------------------------------------------------------------------------
extern "C" void kernel_launch(void* const* d_in, const int* in_sizes, int n_in,
                              void* d_out, int out_size, void* d_ws, size_t ws_size,
                              hipStream_t stream)
{
    const float* input = (const float*)d_in[0];
    const float* encWq = (const float*)d_in[1];
    const float* encWk = (const float*)d_in[2];
    const float* encWv = (const float*)d_in[3];
    const float* encWg = (const float*)d_in[4];
    const float* encbg = (const float*)d_in[5];
    const float* decWq = (const float*)d_in[6];
    const float* decWk = (const float*)d_in[7];
    const float* decWv = (const float*)d_in[8];
    const float* decWg = (const float*)d_in[9];
    const float* decbg = (const float*)d_in[10];
    const float* embW  = (const float*)d_in[11];
    const float* embb  = (const float*)d_in[12];
    const float* outW  = (const float*)d_in[13];
    const float* outb  = (const float*)d_in[14];

    char* ws = (char*)d_ws;
    size_t off = 0;
    auto alloc = [&](size_t bytes) -> void* {
        void* p = ws + off;
        off += (bytes + 255) & ~(size_t)255;
        return p;
    };
    __bf16* Wqkv_e = (__bf16*)alloc((size_t)768*256*2);
    __bf16* Wqkv_d = (__bf16*)alloc((size_t)768*256*2);
    __bf16* Pemb   = (__bf16*)alloc((size_t)256*256*2);
    __bf16* Pg_e   = (__bf16*)alloc((size_t)1024*512*2);
    __bf16* Pg_d   = (__bf16*)alloc((size_t)1024*768*2);
    __bf16* Xa     = (__bf16*)alloc((size_t)Mz*512*2);   // [ehb|dh] ping
    __bf16* Xb     = (__bf16*)alloc((size_t)Mz*512*2);   // pong
    __bf16* q_e    = (__bf16*)alloc((size_t)Mz*256*2);
    __bf16* kv_e   = (__bf16*)alloc((size_t)Mz*512*2);
    __bf16* q_d    = (__bf16*)alloc((size_t)Mz*256*2);
    __bf16* kv_d   = (__bf16*)alloc((size_t)Mz*512*2);
    float*  ec     = (float*) alloc((size_t)Mz*256*4);
    float*  outbuf = (float*) alloc((size_t)NSTEP*Mz*4);

    hipMemsetAsync(Xa, 0, (size_t)Mz*512*2, stream);
    hipMemsetAsync(ec, 0, (size_t)Mz*256*4, stream);
    hipMemsetAsync(outbuf, 0, (size_t)NSTEP*Mz*4, stream);

    prep4<<<6912, 256, 0, stream>>>(encWq, encWk, encWv, encWg,
                                    decWq, decWk, decWv, decWg, embW,
                                    Wqkv_e, Wqkv_d, Pemb, Pg_e, Pg_d);

    for (int t = 0; t < NSTEP; ++t) {
        __bf16* Xp = (t & 1) ? Xb : Xa;
        __bf16* Xq = (t & 1) ? Xa : Xb;
        // D1: enc qkv (ehb_{t-1}) + dec qkv (dh_{t-1}), no duplication
        gemm_qkv2<<<dim3(16,12), 256, 0, stream>>>(Xp, Wqkv_e, Wqkv_d,
                                                   q_e, kv_e, q_d, kv_d);
        // D2: enc attn + gates + LSTM -> ehb_t, ec
        f_enc<<<256, 512, 0, stream>>>(input, t, Xp, Xq, q_e, kv_e,
                                       Pg_e, encWg, encbg, ec);
        // D3: dec attn + code + gates + LSTM + outproj -> dh_t, outbuf
        f_dec<<<256, 512, 0, stream>>>(Xp, Xq, q_d, kv_d, Pemb, Pg_d,
                                       embb, decbg, outW, outbuf + t*Mz);
    }
    assemble_k<<<(Bz*(NSTEP-TPz)*Sz + 255)/256, 256, 0, stream>>>(
        outbuf, input, outb, (float*)d_out);
}

// Round 10
// 1396.541 us; speedup vs baseline: 1.0095x; 1.0095x over previous
//
#include <hip/hip_runtime.h>
#include <hip/hip_bf16.h>

// Problem constants
#define Bz 16
#define Tz 32
#define Sz 128
#define TPz 4
#define Mz (Bz*Sz)          // 2048 rows
#define NSTEP (Tz-1)        // 31

typedef __bf16 bf16x8 __attribute__((ext_vector_type(8)));
typedef float  f32x4  __attribute__((ext_vector_type(4)));

#define MFMA __builtin_amdgcn_mfma_f32_16x16x32_bf16

__device__ __forceinline__ float sigf(float x) { return 1.f/(1.f + __expf(-x)); }

// ---------------------------------------------------------------------------
// prep3 (verified rounds 7/8): pack weights (fp32) into bf16 MFMA B-fragment
// order: P[((nt*KT + kt)*64 + lane)*8 + j] =
//        BT[nt*16 + (lane&15)][kt*32 + (lane>>4)*8 + j]
//  Pqkv_e: [encWq|encWk|encWv]^T  N=768 K=256 (48 nt x 8 kt)
//  Pqkv_d: [decWq|decWk|decWv]^T  N=768 K=256
//  Pemb  : embW^T                 N=256 K=256
//  Pg_e  : enc gates, nt=cht*4+g -> ch=cht*16+(lane&15); K=[h|ctx] (64 nt x 16 kt)
//  Pg_d  : dec gates, K=[code|dh|ctx] (64 nt x 24 kt)
// ---------------------------------------------------------------------------
__global__ __launch_bounds__(256) void prep3(
    const float* __restrict__ encWq, const float* __restrict__ encWk,
    const float* __restrict__ encWv, const float* __restrict__ encWg,
    const float* __restrict__ decWq, const float* __restrict__ decWk,
    const float* __restrict__ decWv, const float* __restrict__ decWg,
    const float* __restrict__ embW,
    __bf16* __restrict__ Pqkv_e, __bf16* __restrict__ Pqkv_d,
    __bf16* __restrict__ Pemb,   __bf16* __restrict__ Pg_e,
    __bf16* __restrict__ Pg_d)
{
    int id = blockIdx.x * 256 + threadIdx.x;
    if (id < 768*256) {
        int f = id >> 9, e = id & 511, l = e >> 3, j = e & 7;
        int nt = f >> 3, kt = f & 7;
        int n = nt*16 + (l & 15), k = kt*32 + (l >> 4)*8 + j;
        float v = (n < 256) ? encWq[k*256 + n]
                : (n < 512) ? encWk[k*256 + (n-256)]
                            : encWv[k*256 + (n-512)];
        Pqkv_e[id] = (__bf16)v; return;
    }
    id -= 768*256;
    if (id < 768*256) {
        int f = id >> 9, e = id & 511, l = e >> 3, j = e & 7;
        int nt = f >> 3, kt = f & 7;
        int n = nt*16 + (l & 15), k = kt*32 + (l >> 4)*8 + j;
        float v = (n < 256) ? decWq[k*256 + n]
                : (n < 512) ? decWk[k*256 + (n-256)]
                            : decWv[k*256 + (n-512)];
        Pqkv_d[id] = (__bf16)v; return;
    }
    id -= 768*256;
    if (id < 256*256) {
        int f = id >> 9, e = id & 511, l = e >> 3, j = e & 7;
        int nt = f >> 3, kt = f & 7;
        int n = nt*16 + (l & 15), k = kt*32 + (l >> 4)*8 + j;
        Pemb[id] = (__bf16)embW[k*256 + n]; return;
    }
    id -= 256*256;
    if (id < 1024*512) {
        int f = id >> 9, e = id & 511, l = e >> 3, j = e & 7;
        int nt = f >> 4, kt = f & 15;
        int cht = nt >> 2, g = nt & 3;
        int ch = cht*16 + (l & 15), k = kt*32 + (l >> 4)*8 + j;
        Pg_e[id] = (__bf16)encWg[(size_t)(3 + k)*1024 + g*256 + ch]; return;
    }
    id -= 1024*512;
    if (id < 1024*768) {
        int f = id >> 9, e = id & 511, l = e >> 3, j = e & 7;
        int nt = f / 24, kt = f % 24;
        int cht = nt >> 2, g = nt & 3;
        int ch = cht*16 + (l & 15), k = kt*32 + (l >> 4)*8 + j;
        Pg_d[id] = (__bf16)decWg[(size_t)k*1024 + g*256 + ch]; return;
    }
}

// ---------------------------------------------------------------------------
// qkv GEMM from 36-row staged state (stride 264) -> qL (own 32 rows), kvL (36).
// (verified rounds 7/8)
// ---------------------------------------------------------------------------
__device__ __forceinline__ void qkv_lds(
    const __bf16* src264, const __bf16* __restrict__ P,
    __bf16* qL, __bf16* kvL, int tid)
{
    const int w = tid >> 6, lane = tid & 63, quad = (lane >> 4), lr = lane & 15;
    #pragma unroll
    for (int ng = 0; ng < 3; ++ng) {
        const int ntA = w*6 + ng*2;
        f32x4 acc[2][3];
        #pragma unroll
        for (int i = 0; i < 2; ++i)
            #pragma unroll
            for (int m = 0; m < 3; ++m) acc[i][m] = f32x4{0.f,0.f,0.f,0.f};
        for (int kt = 0; kt < 8; ++kt) {
            bf16x8 a0 = *(const bf16x8*)&src264[(lr)*264      + kt*32 + quad*8];
            bf16x8 a1 = *(const bf16x8*)&src264[(16 + lr)*264 + kt*32 + quad*8];
            bf16x8 a2 = *(const bf16x8*)&src264[(32 + lr)*264 + kt*32 + quad*8];
            bf16x8 b0 = *(const bf16x8*)&P[((size_t)(ntA*8 + kt)*64 + lane)*8];
            bf16x8 b1 = *(const bf16x8*)&P[((size_t)((ntA+1)*8 + kt)*64 + lane)*8];
            acc[0][0] = MFMA(a0, b0, acc[0][0], 0,0,0);
            acc[0][1] = MFMA(a1, b0, acc[0][1], 0,0,0);
            acc[0][2] = MFMA(a2, b0, acc[0][2], 0,0,0);
            acc[1][0] = MFMA(a0, b1, acc[1][0], 0,0,0);
            acc[1][1] = MFMA(a1, b1, acc[1][1], 0,0,0);
            acc[1][2] = MFMA(a2, b1, acc[1][2], 0,0,0);
        }
        #pragma unroll
        for (int i = 0; i < 2; ++i) {
            const int col = (ntA + i)*16 + lr;
            #pragma unroll
            for (int m = 0; m < 3; ++m)
                #pragma unroll
                for (int r = 0; r < 4; ++r) {
                    const int row = m*16 + quad*4 + r;
                    const float v = acc[i][m][r];
                    if (col < 256) {
                        if (row >= 2 && row < 34) qL[(row-2)*264 + col] = (__bf16)v;
                    } else if (row < 36) {
                        kvL[row*520 + (col - 256)] = (__bf16)v;
                    }
                }
        }
    }
}

// ---------------------------------------------------------------------------
// Attention (32 rows) from LDS qL/kvL -> cxL. (verified rounds 7/8)
// ---------------------------------------------------------------------------
__device__ __forceinline__ void attn_lds(
    const __bf16* qL, const __bf16* kvL, __bf16* cxL, int s0, int tid)
{
    const int w = tid >> 6, lane = tid & 63, quad = lane >> 4, lr = lane & 15;
    const int r = 4*w + quad, s = s0 + r, ch0 = lr*16;

    float q[16];
    {
        bf16x8 q0 = *(const bf16x8*)&qL[r*264 + ch0];
        bf16x8 q1 = *(const bf16x8*)&qL[r*264 + ch0 + 8];
        #pragma unroll
        for (int i = 0; i < 8; ++i) { q[i] = (float)q0[i]; q[8+i] = (float)q1[i]; }
    }
    bf16x8 zv;
    #pragma unroll
    for (int i = 0; i < 8; ++i) zv[i] = (__bf16)0.f;

    const int offs[4] = {2, 1, -1, -2};
    float sc[4]; bf16x8 v0[4], v1[4];
    #pragma unroll
    for (int n = 0; n < 4; ++n) {
        const int s2 = s + offs[n];
        const bool ok = ((unsigned)s2 < 128u);
        const int lrow = r + offs[n] + 2;
        float p = 0.f;
        if (ok) {
            bf16x8 k0 = *(const bf16x8*)&kvL[lrow*520 + ch0];
            bf16x8 k1 = *(const bf16x8*)&kvL[lrow*520 + ch0 + 8];
            v0[n] = *(const bf16x8*)&kvL[lrow*520 + 256 + ch0];
            v1[n] = *(const bf16x8*)&kvL[lrow*520 + 256 + ch0 + 8];
            #pragma unroll
            for (int i = 0; i < 8; ++i) p += q[i]*(float)k0[i] + q[8+i]*(float)k1[i];
        } else { v0[n] = zv; v1[n] = zv; }
        p += __shfl_xor(p, 1);
        sc[n] = ok ? p * 0.17677669529663687f : 0.f;
    }
    const float mx = fmaxf(fmaxf(sc[0], sc[1]), fmaxf(sc[2], sc[3]));
    float se = 0.f, aw[4];
    #pragma unroll
    for (int n = 0; n < 4; ++n) { aw[n] = __expf(sc[n] - mx); se += aw[n]; }
    const float inv = 1.f / se;
    float cx[16];
    #pragma unroll
    for (int i = 0; i < 16; ++i) cx[i] = 0.f;
    #pragma unroll
    for (int n = 0; n < 4; ++n)
        #pragma unroll
        for (int i = 0; i < 8; ++i) {
            cx[i]   += aw[n]*(float)v0[n][i];
            cx[8+i] += aw[n]*(float)v1[n][i];
        }
    bf16x8 o0, o1;
    #pragma unroll
    for (int i = 0; i < 8; ++i) { o0[i] = (__bf16)(cx[i]*inv); o1[i] = (__bf16)(cx[8+i]*inv); }
    *(bf16x8*)&cxL[r*264 + ch0]     = o0;
    *(bf16x8*)&cxL[r*264 + ch0 + 8] = o1;
}

// ---------------------------------------------------------------------------
// step_k: ONE dispatch per scan step k (k = 0..NSTEP).
// blocks 0..255  : dec step td = k-1 (skip if k==0)     [round-8 f_dec body]
// blocks 256..511: enc step te = k   (skip if k==NSTEP) [round-8 f_enc body]
// Buffers: P = buf[k&1], Q = buf[1-(k&1)].
//   enc: reads P.enc (eh_{k-1} halo), writes Q.enc (eh_k), ec.
//   dec: reads P.enc (eh_{td}, code source), Q.dh (dh_{td-1} halo);
//        writes P.dh (dh_{td}), outbuf[td] partial (atomicAdd).
// Disjoint halves => no intra-dispatch hazards.
// ---------------------------------------------------------------------------
#define SM_A264   0                      // 36*264 bf16: enc hL | dec dhL
#define SM_KV     19008                  // 36*520 bf16: kvL
#define SM_Q      56448                  // 32*264 bf16: qL
#define SM_CX     73344                  // 32*264 bf16: cxL
#define SM_EHT    90240                  // 32*264 bf16: dec ehtL
#define SM_CODE   107136                 // 32*264 bf16: dec codeL
#define SM_MISC   124032                 // 512 B: xL / outredL
#define SM_TOTAL  124544

__global__ __launch_bounds__(512, 2) void step_k(
    int k, const float* __restrict__ input,
    __bf16* __restrict__ P, __bf16* __restrict__ Q,
    const __bf16* __restrict__ Pqkv_e, const __bf16* __restrict__ Pqkv_d,
    const __bf16* __restrict__ Pemb,   const __bf16* __restrict__ Pg_e,
    const __bf16* __restrict__ Pg_d,
    const float* __restrict__ encWg, const float* __restrict__ encbg,
    const float* __restrict__ decbg, const float* __restrict__ embb,
    const float* __restrict__ outW,
    float* __restrict__ ec, float* __restrict__ outbuf)
{
    __shared__ __attribute__((aligned(16))) char SM[SM_TOTAL];

    const int tid  = threadIdx.x;
    const int w    = tid >> 6;
    const int lane = tid & 63;
    const int quad = lane >> 4, lr = lane & 15;
    const int mt = w >> 2, ct = w & 3;

    __bf16* hL   = (__bf16*)(SM + SM_A264);
    __bf16* kvL  = (__bf16*)(SM + SM_KV);
    __bf16* qL   = (__bf16*)(SM + SM_Q);
    __bf16* cxL  = (__bf16*)(SM + SM_CX);

    if (blockIdx.x >= 256) {
        // ===================== ENC body (step te = k) =====================
        if (k >= NSTEP) return;
        const int bid = blockIdx.x - 256;
        const int b = bid >> 4, rg = (bid >> 2) & 3, qt = bid & 3;
        const int gbatch = b*128, s0 = rg*32, grow0 = gbatch + s0;
        const int ch = qt*64 + ct*16 + lr;
        float* xL = (float*)(SM + SM_MISC);

        // stage eh_{k-1} halo rows (s0-2 .. s0+33) from P.enc
        for (int v = tid; v < 36*32; v += 512) {
            const int row = v >> 5, seg = v & 31, s = s0 - 2 + row;
            bf16x8 val;
            if ((unsigned)s < 128u)
                val = *(const bf16x8*)&P[(size_t)(gbatch + s)*512 + seg*8];
            else {
                #pragma unroll
                for (int i = 0; i < 8; ++i) val[i] = (__bf16)0.f;
            }
            *(bf16x8*)&hL[row*264 + seg*8] = val;
        }
        if (tid < 96) xL[tid] = input[((size_t)(b*Tz + k)*Sz + s0)*3 + tid];
        __syncthreads();

        qkv_lds(hL, Pqkv_e, qL, kvL, tid);
        __syncthreads();
        attn_lds(qL, kvL, cxL, s0, tid);
        __syncthreads();

        // gates (K=512: hL own rows | cxL) + LSTM
        float wx0[4], wx1[4], wx2[4], bgv[4];
        #pragma unroll
        for (int g = 0; g < 4; ++g) {
            const int c = g*256 + ch;
            wx0[g] = encWg[c]; wx1[g] = encWg[1024 + c]; wx2[g] = encWg[2048 + c];
            bgv[g] = encbg[c];
        }
        f32x4 acc[4];
        #pragma unroll
        for (int g = 0; g < 4; ++g) acc[g] = f32x4{0.f,0.f,0.f,0.f};
        for (int kt = 0; kt < 16; ++kt) {
            const __bf16* As = (kt < 8)
                ? &hL [(2 + mt*16 + lr)*264 + kt*32 + quad*8]
                : &cxL[(mt*16 + lr)*264 + (kt-8)*32 + quad*8];
            bf16x8 af = *(const bf16x8*)As;
            #pragma unroll
            for (int g = 0; g < 4; ++g) {
                const int nt = qt*16 + ct*4 + g;
                bf16x8 bf = *(const bf16x8*)&Pg_e[((size_t)(nt*16 + kt)*64 + lane)*8];
                acc[g] = MFMA(af, bf, acc[g], 0,0,0);
            }
        }
        #pragma unroll
        for (int r = 0; r < 4; ++r) {
            const int row = mt*16 + quad*4 + r;
            const float x0 = xL[row*3], x1 = xL[row*3+1], x2 = xL[row*3+2];
            const float zi = acc[0][r] + x0*wx0[0] + x1*wx1[0] + x2*wx2[0] + bgv[0];
            const float zf = acc[1][r] + x0*wx0[1] + x1*wx1[1] + x2*wx2[1] + bgv[1];
            const float zg = acc[2][r] + x0*wx0[2] + x1*wx1[2] + x2*wx2[2] + bgv[2];
            const float zo = acc[3][r] + x0*wx0[3] + x1*wx1[3] + x2*wx2[3] + bgv[3];
            const size_t ei = (size_t)(grow0 + row)*256 + ch;
            const float cn = sigf(zf)*ec[ei] + sigf(zi)*tanhf(zg);
            ec[ei] = cn;
            Q[(size_t)(grow0 + row)*512 + ch] = (__bf16)(sigf(zo)*tanhf(cn));
        }
    } else {
        // ===================== DEC body (step td = k-1) =====================
        if (k < 1) return;
        const int td = k - 1;
        const int bid = blockIdx.x;
        const int b = bid >> 4, rg = (bid >> 2) & 3, qt = bid & 3;
        const int gbatch = b*128, s0 = rg*32, grow0 = gbatch + s0;
        const int ch = qt*64 + ct*16 + lr;
        __bf16* dhL   = hL;                         // alias (36*264)
        __bf16* ehtL  = (__bf16*)(SM + SM_EHT);
        __bf16* codeL = (__bf16*)(SM + SM_CODE);
        float* outredL = (float*)(SM + SM_MISC);

        // stage eh_{td} own rows (P.enc) + dh_{td-1} halo (Q.dh)
        for (int v = tid; v < 32*32; v += 512) {
            const int row = v >> 5, seg = v & 31;
            *(bf16x8*)&ehtL[row*264 + seg*8] =
                *(const bf16x8*)&P[(size_t)(grow0 + row)*512 + seg*8];
        }
        for (int v = tid; v < 36*32; v += 512) {
            const int row = v >> 5, seg = v & 31, s = s0 - 2 + row;
            bf16x8 val;
            if ((unsigned)s < 128u)
                val = *(const bf16x8*)&Q[(size_t)(gbatch + s)*512 + 256 + seg*8];
            else {
                #pragma unroll
                for (int i = 0; i < 8; ++i) val[i] = (__bf16)0.f;
            }
            *(bf16x8*)&dhL[row*264 + seg*8] = val;
        }
        __syncthreads();

        // code = sig(eh_{td} @ embW + embb) -> codeL
        {
            f32x4 cacc[2][2];
            #pragma unroll
            for (int m = 0; m < 2; ++m)
                #pragma unroll
                for (int i = 0; i < 2; ++i) cacc[m][i] = f32x4{0.f,0.f,0.f,0.f};
            for (int kt = 0; kt < 8; ++kt) {
                bf16x8 a0 = *(const bf16x8*)&ehtL[(lr)*264      + kt*32 + quad*8];
                bf16x8 a1 = *(const bf16x8*)&ehtL[(16 + lr)*264 + kt*32 + quad*8];
                #pragma unroll
                for (int i = 0; i < 2; ++i) {
                    bf16x8 bf = *(const bf16x8*)&Pemb[((size_t)((2*w + i)*8 + kt)*64 + lane)*8];
                    cacc[0][i] = MFMA(a0, bf, cacc[0][i], 0,0,0);
                    cacc[1][i] = MFMA(a1, bf, cacc[1][i], 0,0,0);
                }
            }
            #pragma unroll
            for (int i = 0; i < 2; ++i) {
                const int col = (2*w + i)*16 + lr;
                const float bb = embb[col];
                #pragma unroll
                for (int m = 0; m < 2; ++m)
                    #pragma unroll
                    for (int r = 0; r < 4; ++r)
                        codeL[(m*16 + quad*4 + r)*264 + col] = (__bf16)sigf(cacc[m][i][r] + bb);
            }
        }
        // dec qkv from dh_{td-1} halo
        qkv_lds(dhL, Pqkv_d, qL, kvL, tid);
        __syncthreads();
        attn_lds(qL, kvL, cxL, s0, tid);
        __syncthreads();

        // gates (K=768: codeL | dhL own | cxL) + LSTM + outproj
        float bgv[4];
        #pragma unroll
        for (int g = 0; g < 4; ++g) bgv[g] = decbg[g*256 + ch];
        const float ow = outW[ch];

        f32x4 acc[4];
        #pragma unroll
        for (int g = 0; g < 4; ++g) acc[g] = f32x4{0.f,0.f,0.f,0.f};
        for (int kt = 0; kt < 24; ++kt) {
            const __bf16* As = (kt < 8)
                ? &codeL[(mt*16 + lr)*264 + kt*32 + quad*8]
                : (kt < 16)
                ? &dhL[(2 + mt*16 + lr)*264 + (kt-8)*32 + quad*8]
                : &cxL[(mt*16 + lr)*264 + (kt-16)*32 + quad*8];
            bf16x8 af = *(const bf16x8*)As;
            #pragma unroll
            for (int g = 0; g < 4; ++g) {
                const int nt = qt*16 + ct*4 + g;
                bf16x8 bf = *(const bf16x8*)&Pg_d[((size_t)(nt*24 + kt)*64 + lane)*8];
                acc[g] = MFMA(af, bf, acc[g], 0,0,0);
            }
        }
        #pragma unroll
        for (int r = 0; r < 4; ++r) {
            const int row = mt*16 + quad*4 + r;
            const float zi = acc[0][r] + bgv[0];
            const float zf = acc[1][r] + bgv[1];
            const float zg = acc[2][r] + bgv[2];
            const float zo = acc[3][r] + bgv[3];
            const float c_old = (float)dhL[(2 + row)*264 + ch];
            const float cn = sigf(zf)*c_old + sigf(zi)*tanhf(zg);
            const float h  = sigf(zo)*tanhf(cn);
            P[(size_t)(grow0 + row)*512 + 256 + ch] = (__bf16)h;
            float pv = h * ow;
            pv += __shfl_xor(pv, 1); pv += __shfl_xor(pv, 2);
            pv += __shfl_xor(pv, 4); pv += __shfl_xor(pv, 8);
            if (lr == 0) outredL[row*4 + ct] = pv;
        }
        __syncthreads();
        if (tid < 32) {
            const float s4 = outredL[tid*4] + outredL[tid*4+1]
                           + outredL[tid*4+2] + outredL[tid*4+3];
            atomicAdd(&outbuf[(size_t)td*Mz + grow0 + tid], s4);
        }
    }
}

// ---------------------------------------------------------------------------
// Final assembly (unchanged, verified)
// ---------------------------------------------------------------------------
__global__ __launch_bounds__(256) void assemble_k(
    const float* __restrict__ outbuf, const float* __restrict__ input,
    const float* __restrict__ outb, float* __restrict__ out)
{
    const int idx = blockIdx.x*256 + threadIdx.x;
    const int NT = NSTEP - TPz;                 // 27
    if (idx >= Bz*NT*Sz) return;
    const int s  = idx & 127;
    const int bi = idx >> 7;
    const int i  = bi % NT;
    const int b  = bi / NT;
    const int t  = i + TPz;
    const float ob = outb[0];
    const float o  = outbuf[t*Mz + (b<<7) + s] + ob;
    const float In = (s == 0)
        ? input[((size_t)(b*Tz + t + 1)*Sz)*3 + 1]
        : outbuf[t*Mz + (b<<7) + s - 1] + ob;
    const float num = input[((size_t)(b*Tz + t)*Sz + s)*3 + 2] + In - o;
    const size_t base = ((size_t)(b*NT + i)*Sz + s)*3;
    out[base+0] = o;
    out[base+1] = In;
    out[base+2] = num;
}

// ---------------------------------------------------------------------------
extern "C" void kernel_launch(void* const* d_in, const int* in_sizes, int n_in,
                              void* d_out, int out_size, void* d_ws, size_t ws_size,
                              hipStream_t stream)
{
    const float* input = (const float*)d_in[0];
    const float* encWq = (const float*)d_in[1];
    const float* encWk = (const float*)d_in[2];
    const float* encWv = (const float*)d_in[3];
    const float* encWg = (const float*)d_in[4];
    const float* encbg = (const float*)d_in[5];
    const float* decWq = (const float*)d_in[6];
    const float* decWk = (const float*)d_in[7];
    const float* decWv = (const float*)d_in[8];
    const float* decWg = (const float*)d_in[9];
    const float* decbg = (const float*)d_in[10];
    const float* embW  = (const float*)d_in[11];
    const float* embb  = (const float*)d_in[12];
    const float* outW  = (const float*)d_in[13];
    const float* outb  = (const float*)d_in[14];

    char* ws = (char*)d_ws;
    size_t off = 0;
    auto alloc = [&](size_t bytes) -> void* {
        void* p = ws + off;
        off += (bytes + 255) & ~(size_t)255;
        return p;
    };
    __bf16* Pqkv_e = (__bf16*)alloc((size_t)768*256*2);
    __bf16* Pqkv_d = (__bf16*)alloc((size_t)768*256*2);
    __bf16* Pemb   = (__bf16*)alloc((size_t)256*256*2);
    __bf16* Pg_e   = (__bf16*)alloc((size_t)1024*512*2);
    __bf16* Pg_d   = (__bf16*)alloc((size_t)1024*768*2);
    __bf16* Xa     = (__bf16*)alloc((size_t)Mz*512*2);   // [ehb|dh] ping
    __bf16* Xb     = (__bf16*)alloc((size_t)Mz*512*2);   // pong
    float*  ec     = (float*) alloc((size_t)Mz*256*4);
    float*  outbuf = (float*) alloc((size_t)NSTEP*Mz*4);

    hipMemsetAsync(Xa, 0, (size_t)Mz*512*2, stream);
    hipMemsetAsync(ec, 0, (size_t)Mz*256*4, stream);
    hipMemsetAsync(outbuf, 0, (size_t)NSTEP*Mz*4, stream);

    prep3<<<6912, 256, 0, stream>>>(encWq, encWk, encWv, encWg,
                                    decWq, decWk, decWv, decWg, embW,
                                    Pqkv_e, Pqkv_d, Pemb, Pg_e, Pg_d);

    for (int k = 0; k <= NSTEP; ++k) {
        __bf16* P = (k & 1) ? Xb : Xa;
        __bf16* Q = (k & 1) ? Xa : Xb;
        step_k<<<512, 512, 0, stream>>>(k, input, P, Q,
                                        Pqkv_e, Pqkv_d, Pemb, Pg_e, Pg_d,
                                        encWg, encbg, decbg, embb, outW,
                                        ec, outbuf);
    }
    assemble_k<<<(Bz*(NSTEP-TPz)*Sz + 255)/256, 256, 0, stream>>>(
        outbuf, input, outb, (float*)d_out);
}

// Round 11
// 1278.640 us; speedup vs baseline: 1.1025x; 1.0922x over previous
//
#include <hip/hip_runtime.h>
#include <hip/hip_bf16.h>

// Problem constants
#define Bz 16
#define Tz 32
#define Sz 128
#define TPz 4
#define Mz (Bz*Sz)          // 2048 rows
#define NSTEP (Tz-1)        // 31

typedef __bf16 bf16x8 __attribute__((ext_vector_type(8)));
typedef float  f32x4  __attribute__((ext_vector_type(4)));

#define MFMA __builtin_amdgcn_mfma_f32_16x16x32_bf16

__device__ __forceinline__ float sigf(float x) { return 1.f/(1.f + __expf(-x)); }

// ---------------------------------------------------------------------------
// prep3 (verified rounds 7/8/10): pack weights (fp32) into bf16 MFMA B-fragment
// order: P[((nt*KT + kt)*64 + lane)*8 + j] =
//        BT[nt*16 + (lane&15)][kt*32 + (lane>>4)*8 + j]
// ---------------------------------------------------------------------------
__global__ __launch_bounds__(256) void prep3(
    const float* __restrict__ encWq, const float* __restrict__ encWk,
    const float* __restrict__ encWv, const float* __restrict__ encWg,
    const float* __restrict__ decWq, const float* __restrict__ decWk,
    const float* __restrict__ decWv, const float* __restrict__ decWg,
    const float* __restrict__ embW,
    __bf16* __restrict__ Pqkv_e, __bf16* __restrict__ Pqkv_d,
    __bf16* __restrict__ Pemb,   __bf16* __restrict__ Pg_e,
    __bf16* __restrict__ Pg_d)
{
    int id = blockIdx.x * 256 + threadIdx.x;
    if (id < 768*256) {
        int f = id >> 9, e = id & 511, l = e >> 3, j = e & 7;
        int nt = f >> 3, kt = f & 7;
        int n = nt*16 + (l & 15), k = kt*32 + (l >> 4)*8 + j;
        float v = (n < 256) ? encWq[k*256 + n]
                : (n < 512) ? encWk[k*256 + (n-256)]
                            : encWv[k*256 + (n-512)];
        Pqkv_e[id] = (__bf16)v; return;
    }
    id -= 768*256;
    if (id < 768*256) {
        int f = id >> 9, e = id & 511, l = e >> 3, j = e & 7;
        int nt = f >> 3, kt = f & 7;
        int n = nt*16 + (l & 15), k = kt*32 + (l >> 4)*8 + j;
        float v = (n < 256) ? decWq[k*256 + n]
                : (n < 512) ? decWk[k*256 + (n-256)]
                            : decWv[k*256 + (n-512)];
        Pqkv_d[id] = (__bf16)v; return;
    }
    id -= 768*256;
    if (id < 256*256) {
        int f = id >> 9, e = id & 511, l = e >> 3, j = e & 7;
        int nt = f >> 3, kt = f & 7;
        int n = nt*16 + (l & 15), k = kt*32 + (l >> 4)*8 + j;
        Pemb[id] = (__bf16)embW[k*256 + n]; return;
    }
    id -= 256*256;
    if (id < 1024*512) {
        int f = id >> 9, e = id & 511, l = e >> 3, j = e & 7;
        int nt = f >> 4, kt = f & 15;
        int cht = nt >> 2, g = nt & 3;
        int ch = cht*16 + (l & 15), k = kt*32 + (l >> 4)*8 + j;
        Pg_e[id] = (__bf16)encWg[(size_t)(3 + k)*1024 + g*256 + ch]; return;
    }
    id -= 1024*512;
    if (id < 1024*768) {
        int f = id >> 9, e = id & 511, l = e >> 3, j = e & 7;
        int nt = f / 24, kt = f % 24;
        int cht = nt >> 2, g = nt & 3;
        int ch = cht*16 + (l & 15), k = kt*32 + (l >> 4)*8 + j;
        Pg_d[id] = (__bf16)decWg[(size_t)k*1024 + g*256 + ch]; return;
    }
}

// ---------------------------------------------------------------------------
// qkv GEMM from 36-row staged state (stride 264) -> qL (own 32 rows), kvL (36).
// (verified rounds 7/8/10)
// ---------------------------------------------------------------------------
__device__ __forceinline__ void qkv_lds(
    const __bf16* src264, const __bf16* __restrict__ P,
    __bf16* qL, __bf16* kvL, int tid)
{
    const int w = tid >> 6, lane = tid & 63, quad = (lane >> 4), lr = lane & 15;
    #pragma unroll
    for (int ng = 0; ng < 3; ++ng) {
        const int ntA = w*6 + ng*2;
        f32x4 acc[2][3];
        #pragma unroll
        for (int i = 0; i < 2; ++i)
            #pragma unroll
            for (int m = 0; m < 3; ++m) acc[i][m] = f32x4{0.f,0.f,0.f,0.f};
        for (int kt = 0; kt < 8; ++kt) {
            bf16x8 a0 = *(const bf16x8*)&src264[(lr)*264      + kt*32 + quad*8];
            bf16x8 a1 = *(const bf16x8*)&src264[(16 + lr)*264 + kt*32 + quad*8];
            bf16x8 a2 = *(const bf16x8*)&src264[(32 + lr)*264 + kt*32 + quad*8];
            bf16x8 b0 = *(const bf16x8*)&P[((size_t)(ntA*8 + kt)*64 + lane)*8];
            bf16x8 b1 = *(const bf16x8*)&P[((size_t)((ntA+1)*8 + kt)*64 + lane)*8];
            acc[0][0] = MFMA(a0, b0, acc[0][0], 0,0,0);
            acc[0][1] = MFMA(a1, b0, acc[0][1], 0,0,0);
            acc[0][2] = MFMA(a2, b0, acc[0][2], 0,0,0);
            acc[1][0] = MFMA(a0, b1, acc[1][0], 0,0,0);
            acc[1][1] = MFMA(a1, b1, acc[1][1], 0,0,0);
            acc[1][2] = MFMA(a2, b1, acc[1][2], 0,0,0);
        }
        #pragma unroll
        for (int i = 0; i < 2; ++i) {
            const int col = (ntA + i)*16 + lr;
            #pragma unroll
            for (int m = 0; m < 3; ++m)
                #pragma unroll
                for (int r = 0; r < 4; ++r) {
                    const int row = m*16 + quad*4 + r;
                    const float v = acc[i][m][r];
                    if (col < 256) {
                        if (row >= 2 && row < 34) qL[(row-2)*264 + col] = (__bf16)v;
                    } else if (row < 36) {
                        kvL[row*520 + (col - 256)] = (__bf16)v;
                    }
                }
        }
    }
}

// ---------------------------------------------------------------------------
// Attention (32 rows) from LDS qL/kvL -> cxL. (verified rounds 7/8/10)
// cxL MAY alias qL: each lane reads only the q chunk it later overwrites.
// ---------------------------------------------------------------------------
__device__ __forceinline__ void attn_lds(
    const __bf16* qL, const __bf16* kvL, __bf16* cxL, int s0, int tid)
{
    const int w = tid >> 6, lane = tid & 63, quad = lane >> 4, lr = lane & 15;
    const int r = 4*w + quad, s = s0 + r, ch0 = lr*16;

    float q[16];
    {
        bf16x8 q0 = *(const bf16x8*)&qL[r*264 + ch0];
        bf16x8 q1 = *(const bf16x8*)&qL[r*264 + ch0 + 8];
        #pragma unroll
        for (int i = 0; i < 8; ++i) { q[i] = (float)q0[i]; q[8+i] = (float)q1[i]; }
    }
    bf16x8 zv;
    #pragma unroll
    for (int i = 0; i < 8; ++i) zv[i] = (__bf16)0.f;

    const int offs[4] = {2, 1, -1, -2};
    float sc[4]; bf16x8 v0[4], v1[4];
    #pragma unroll
    for (int n = 0; n < 4; ++n) {
        const int s2 = s + offs[n];
        const bool ok = ((unsigned)s2 < 128u);
        const int lrow = r + offs[n] + 2;
        float p = 0.f;
        if (ok) {
            bf16x8 k0 = *(const bf16x8*)&kvL[lrow*520 + ch0];
            bf16x8 k1 = *(const bf16x8*)&kvL[lrow*520 + ch0 + 8];
            v0[n] = *(const bf16x8*)&kvL[lrow*520 + 256 + ch0];
            v1[n] = *(const bf16x8*)&kvL[lrow*520 + 256 + ch0 + 8];
            #pragma unroll
            for (int i = 0; i < 8; ++i) p += q[i]*(float)k0[i] + q[8+i]*(float)k1[i];
        } else { v0[n] = zv; v1[n] = zv; }
        p += __shfl_xor(p, 1);
        sc[n] = ok ? p * 0.17677669529663687f : 0.f;
    }
    const float mx = fmaxf(fmaxf(sc[0], sc[1]), fmaxf(sc[2], sc[3]));
    float se = 0.f, aw[4];
    #pragma unroll
    for (int n = 0; n < 4; ++n) { aw[n] = __expf(sc[n] - mx); se += aw[n]; }
    const float inv = 1.f / se;
    float cx[16];
    #pragma unroll
    for (int i = 0; i < 16; ++i) cx[i] = 0.f;
    #pragma unroll
    for (int n = 0; n < 4; ++n)
        #pragma unroll
        for (int i = 0; i < 8; ++i) {
            cx[i]   += aw[n]*(float)v0[n][i];
            cx[8+i] += aw[n]*(float)v1[n][i];
        }
    bf16x8 o0, o1;
    #pragma unroll
    for (int i = 0; i < 8; ++i) { o0[i] = (__bf16)(cx[i]*inv); o1[i] = (__bf16)(cx[8+i]*inv); }
    *(bf16x8*)&cxL[r*264 + ch0]     = o0;
    *(bf16x8*)&cxL[r*264 + ch0 + 8] = o1;
}

// ---------------------------------------------------------------------------
// step_k: ONE dispatch per scan step k (k = 0..NSTEP).
// blocks 0..255  : dec step td = k-1 (skip if k==0)
// blocks 256..511: enc step te = k   (skip if k==NSTEP)
// LDS arena 73856 B -> 2 blocks/CU co-resident (enc+dec overlap per CU).
//   [0      .. 19008) A264  : enc hL / dec dhL (36*264)
//   [19008  .. 56448) R     : enc kvL (36*520)
//                             dec: ehtL@19008 (32*264), codeL@35904 (32*264),
//                                  then kvL@19008 (36*520) after both are dead
//   [56448  .. 73344) Q     : qL (32*264); cxL aliases qL (lane-private RAW)
//   [73344  .. 73856) misc  : xL / outredL
// Dec gate acc order unchanged (code kt0..7 first) -> bitwise-identical math.
// ---------------------------------------------------------------------------
#define SM_A264   0
#define SM_R      19008
#define SM_CODE   35904
#define SM_Q      56448
#define SM_MISC   73344
#define SM_TOTAL  73856

__global__ __launch_bounds__(512, 4) void step_k(
    int k, const float* __restrict__ input,
    __bf16* __restrict__ P, __bf16* __restrict__ Q,
    const __bf16* __restrict__ Pqkv_e, const __bf16* __restrict__ Pqkv_d,
    const __bf16* __restrict__ Pemb,   const __bf16* __restrict__ Pg_e,
    const __bf16* __restrict__ Pg_d,
    const float* __restrict__ encWg, const float* __restrict__ encbg,
    const float* __restrict__ decbg, const float* __restrict__ embb,
    const float* __restrict__ outW,
    float* __restrict__ ec, float* __restrict__ outbuf)
{
    __shared__ __attribute__((aligned(16))) char SM[SM_TOTAL];

    const int tid  = threadIdx.x;
    const int w    = tid >> 6;
    const int lane = tid & 63;
    const int quad = lane >> 4, lr = lane & 15;
    const int mt = w >> 2, ct = w & 3;

    __bf16* aL  = (__bf16*)(SM + SM_A264);   // hL / dhL
    __bf16* kvL = (__bf16*)(SM + SM_R);
    __bf16* qL  = (__bf16*)(SM + SM_Q);
    __bf16* cxL = qL;                        // alias (safe, see attn_lds)

    if (blockIdx.x >= 256) {
        // ===================== ENC body (step te = k) =====================
        if (k >= NSTEP) return;
        const int bid = blockIdx.x - 256;
        const int b = bid >> 4, rg = (bid >> 2) & 3, qt = bid & 3;
        const int gbatch = b*128, s0 = rg*32, grow0 = gbatch + s0;
        const int ch = qt*64 + ct*16 + lr;
        float* xL = (float*)(SM + SM_MISC);

        // stage eh_{k-1} halo rows (s0-2 .. s0+33) from P.enc
        for (int v = tid; v < 36*32; v += 512) {
            const int row = v >> 5, seg = v & 31, s = s0 - 2 + row;
            bf16x8 val;
            if ((unsigned)s < 128u)
                val = *(const bf16x8*)&P[(size_t)(gbatch + s)*512 + seg*8];
            else {
                #pragma unroll
                for (int i = 0; i < 8; ++i) val[i] = (__bf16)0.f;
            }
            *(bf16x8*)&aL[row*264 + seg*8] = val;
        }
        if (tid < 96) xL[tid] = input[((size_t)(b*Tz + k)*Sz + s0)*3 + tid];
        __syncthreads();

        qkv_lds(aL, Pqkv_e, qL, kvL, tid);
        __syncthreads();
        attn_lds(qL, kvL, cxL, s0, tid);
        __syncthreads();

        // gates (K=512: aL own rows | cxL) + LSTM
        float wx0[4], wx1[4], wx2[4], bgv[4];
        #pragma unroll
        for (int g = 0; g < 4; ++g) {
            const int c = g*256 + ch;
            wx0[g] = encWg[c]; wx1[g] = encWg[1024 + c]; wx2[g] = encWg[2048 + c];
            bgv[g] = encbg[c];
        }
        f32x4 acc[4];
        #pragma unroll
        for (int g = 0; g < 4; ++g) acc[g] = f32x4{0.f,0.f,0.f,0.f};
        for (int kt = 0; kt < 16; ++kt) {
            const __bf16* As = (kt < 8)
                ? &aL [(2 + mt*16 + lr)*264 + kt*32 + quad*8]
                : &cxL[(mt*16 + lr)*264 + (kt-8)*32 + quad*8];
            bf16x8 af = *(const bf16x8*)As;
            #pragma unroll
            for (int g = 0; g < 4; ++g) {
                const int nt = qt*16 + ct*4 + g;
                bf16x8 bf = *(const bf16x8*)&Pg_e[((size_t)(nt*16 + kt)*64 + lane)*8];
                acc[g] = MFMA(af, bf, acc[g], 0,0,0);
            }
        }
        #pragma unroll
        for (int r = 0; r < 4; ++r) {
            const int row = mt*16 + quad*4 + r;
            const float x0 = xL[row*3], x1 = xL[row*3+1], x2 = xL[row*3+2];
            const float zi = acc[0][r] + x0*wx0[0] + x1*wx1[0] + x2*wx2[0] + bgv[0];
            const float zf = acc[1][r] + x0*wx0[1] + x1*wx1[1] + x2*wx2[1] + bgv[1];
            const float zg = acc[2][r] + x0*wx0[2] + x1*wx1[2] + x2*wx2[2] + bgv[2];
            const float zo = acc[3][r] + x0*wx0[3] + x1*wx1[3] + x2*wx2[3] + bgv[3];
            const size_t ei = (size_t)(grow0 + row)*256 + ch;
            const float cn = sigf(zf)*ec[ei] + sigf(zi)*tanhf(zg);
            ec[ei] = cn;
            Q[(size_t)(grow0 + row)*512 + ch] = (__bf16)(sigf(zo)*tanhf(cn));
        }
    } else {
        // ===================== DEC body (step td = k-1) =====================
        if (k < 1) return;
        const int td = k - 1;
        const int bid = blockIdx.x;
        const int b = bid >> 4, rg = (bid >> 2) & 3, qt = bid & 3;
        const int gbatch = b*128, s0 = rg*32, grow0 = gbatch + s0;
        const int ch = qt*64 + ct*16 + lr;
        __bf16* dhL   = aL;
        __bf16* ehtL  = (__bf16*)(SM + SM_R);      // dead after code GEMM
        __bf16* codeL = (__bf16*)(SM + SM_CODE);   // dead after gates code-part
        float* outredL = (float*)(SM + SM_MISC);

        // stage eh_{td} own rows (P.enc) + dh_{td-1} halo (Q.dh)
        for (int v = tid; v < 32*32; v += 512) {
            const int row = v >> 5, seg = v & 31;
            *(bf16x8*)&ehtL[row*264 + seg*8] =
                *(const bf16x8*)&P[(size_t)(grow0 + row)*512 + seg*8];
        }
        for (int v = tid; v < 36*32; v += 512) {
            const int row = v >> 5, seg = v & 31, s = s0 - 2 + row;
            bf16x8 val;
            if ((unsigned)s < 128u)
                val = *(const bf16x8*)&Q[(size_t)(gbatch + s)*512 + 256 + seg*8];
            else {
                #pragma unroll
                for (int i = 0; i < 8; ++i) val[i] = (__bf16)0.f;
            }
            *(bf16x8*)&dhL[row*264 + seg*8] = val;
        }
        __syncthreads();

        // code = sig(eh_{td} @ embW + embb) -> codeL
        {
            f32x4 cacc[2][2];
            #pragma unroll
            for (int m = 0; m < 2; ++m)
                #pragma unroll
                for (int i = 0; i < 2; ++i) cacc[m][i] = f32x4{0.f,0.f,0.f,0.f};
            for (int kt = 0; kt < 8; ++kt) {
                bf16x8 a0 = *(const bf16x8*)&ehtL[(lr)*264      + kt*32 + quad*8];
                bf16x8 a1 = *(const bf16x8*)&ehtL[(16 + lr)*264 + kt*32 + quad*8];
                #pragma unroll
                for (int i = 0; i < 2; ++i) {
                    bf16x8 bf = *(const bf16x8*)&Pemb[((size_t)((2*w + i)*8 + kt)*64 + lane)*8];
                    cacc[0][i] = MFMA(a0, bf, cacc[0][i], 0,0,0);
                    cacc[1][i] = MFMA(a1, bf, cacc[1][i], 0,0,0);
                }
            }
            __syncthreads();   // all ehtL reads done before codeL writes (disjoint anyway)
            #pragma unroll
            for (int i = 0; i < 2; ++i) {
                const int col = (2*w + i)*16 + lr;
                const float bb = embb[col];
                #pragma unroll
                for (int m = 0; m < 2; ++m)
                    #pragma unroll
                    for (int r = 0; r < 4; ++r)
                        codeL[(m*16 + quad*4 + r)*264 + col] = (__bf16)sigf(cacc[m][i][r] + bb);
            }
        }
        __syncthreads();

        // gates acc: code part FIRST (kt 0..7) so codeL dies before kvL overlay
        float bgv[4];
        #pragma unroll
        for (int g = 0; g < 4; ++g) bgv[g] = decbg[g*256 + ch];
        const float ow = outW[ch];

        f32x4 acc[4];
        #pragma unroll
        for (int g = 0; g < 4; ++g) acc[g] = f32x4{0.f,0.f,0.f,0.f};
        for (int kt = 0; kt < 8; ++kt) {
            bf16x8 af = *(const bf16x8*)&codeL[(mt*16 + lr)*264 + kt*32 + quad*8];
            #pragma unroll
            for (int g = 0; g < 4; ++g) {
                const int nt = qt*16 + ct*4 + g;
                bf16x8 bf = *(const bf16x8*)&Pg_d[((size_t)(nt*24 + kt)*64 + lane)*8];
                acc[g] = MFMA(af, bf, acc[g], 0,0,0);
            }
        }
        __syncthreads();   // codeL/ehtL dead; kvL may now overwrite region R

        // dec qkv from dh_{td-1} halo (kvL overlays ehtL+codeL region)
        qkv_lds(dhL, Pqkv_d, qL, kvL, tid);
        __syncthreads();
        attn_lds(qL, kvL, cxL, s0, tid);
        __syncthreads();

        // gates rest (kt 8..23: dhL own | cxL) + LSTM + outproj
        for (int kt = 8; kt < 24; ++kt) {
            const __bf16* As = (kt < 16)
                ? &dhL[(2 + mt*16 + lr)*264 + (kt-8)*32 + quad*8]
                : &cxL[(mt*16 + lr)*264 + (kt-16)*32 + quad*8];
            bf16x8 af = *(const bf16x8*)As;
            #pragma unroll
            for (int g = 0; g < 4; ++g) {
                const int nt = qt*16 + ct*4 + g;
                bf16x8 bf = *(const bf16x8*)&Pg_d[((size_t)(nt*24 + kt)*64 + lane)*8];
                acc[g] = MFMA(af, bf, acc[g], 0,0,0);
            }
        }
        #pragma unroll
        for (int r = 0; r < 4; ++r) {
            const int row = mt*16 + quad*4 + r;
            const float zi = acc[0][r] + bgv[0];
            const float zf = acc[1][r] + bgv[1];
            const float zg = acc[2][r] + bgv[2];
            const float zo = acc[3][r] + bgv[3];
            const float c_old = (float)dhL[(2 + row)*264 + ch];
            const float cn = sigf(zf)*c_old + sigf(zi)*tanhf(zg);
            const float h  = sigf(zo)*tanhf(cn);
            P[(size_t)(grow0 + row)*512 + 256 + ch] = (__bf16)h;
            float pv = h * ow;
            pv += __shfl_xor(pv, 1); pv += __shfl_xor(pv, 2);
            pv += __shfl_xor(pv, 4); pv += __shfl_xor(pv, 8);
            if (lr == 0) outredL[row*4 + ct] = pv;
        }
        __syncthreads();
        if (tid < 32) {
            const float s4 = outredL[tid*4] + outredL[tid*4+1]
                           + outredL[tid*4+2] + outredL[tid*4+3];
            atomicAdd(&outbuf[(size_t)td*Mz + grow0 + tid], s4);
        }
    }
}

// ---------------------------------------------------------------------------
// Final assembly (unchanged, verified)
// ---------------------------------------------------------------------------
__global__ __launch_bounds__(256) void assemble_k(
    const float* __restrict__ outbuf, const float* __restrict__ input,
    const float* __restrict__ outb, float* __restrict__ out)
{
    const int idx = blockIdx.x*256 + threadIdx.x;
    const int NT = NSTEP - TPz;                 // 27
    if (idx >= Bz*NT*Sz) return;
    const int s  = idx & 127;
    const int bi = idx >> 7;
    const int i  = bi % NT;
    const int b  = bi / NT;
    const int t  = i + TPz;
    const float ob = outb[0];
    const float o  = outbuf[t*Mz + (b<<7) + s] + ob;
    const float In = (s == 0)
        ? input[((size_t)(b*Tz + t + 1)*Sz)*3 + 1]
        : outbuf[t*Mz + (b<<7) + s - 1] + ob;
    const float num = input[((size_t)(b*Tz + t)*Sz + s)*3 + 2] + In - o;
    const size_t base = ((size_t)(b*NT + i)*Sz + s)*3;
    out[base+0] = o;
    out[base+1] = In;
    out[base+2] = num;
}

// ---------------------------------------------------------------------------
extern "C" void kernel_launch(void* const* d_in, const int* in_sizes, int n_in,
                              void* d_out, int out_size, void* d_ws, size_t ws_size,
                              hipStream_t stream)
{
    const float* input = (const float*)d_in[0];
    const float* encWq = (const float*)d_in[1];
    const float* encWk = (const float*)d_in[2];
    const float* encWv = (const float*)d_in[3];
    const float* encWg = (const float*)d_in[4];
    const float* encbg = (const float*)d_in[5];
    const float* decWq = (const float*)d_in[6];
    const float* decWk = (const float*)d_in[7];
    const float* decWv = (const float*)d_in[8];
    const float* decWg = (const float*)d_in[9];
    const float* decbg = (const float*)d_in[10];
    const float* embW  = (const float*)d_in[11];
    const float* embb  = (const float*)d_in[12];
    const float* outW  = (const float*)d_in[13];
    const float* outb  = (const float*)d_in[14];

    char* ws = (char*)d_ws;
    size_t off = 0;
    auto alloc = [&](size_t bytes) -> void* {
        void* p = ws + off;
        off += (bytes + 255) & ~(size_t)255;
        return p;
    };
    __bf16* Pqkv_e = (__bf16*)alloc((size_t)768*256*2);
    __bf16* Pqkv_d = (__bf16*)alloc((size_t)768*256*2);
    __bf16* Pemb   = (__bf16*)alloc((size_t)256*256*2);
    __bf16* Pg_e   = (__bf16*)alloc((size_t)1024*512*2);
    __bf16* Pg_d   = (__bf16*)alloc((size_t)1024*768*2);
    __bf16* Xa     = (__bf16*)alloc((size_t)Mz*512*2);   // [ehb|dh] ping
    __bf16* Xb     = (__bf16*)alloc((size_t)Mz*512*2);   // pong
    float*  ec     = (float*) alloc((size_t)Mz*256*4);
    float*  outbuf = (float*) alloc((size_t)NSTEP*Mz*4);

    hipMemsetAsync(Xa, 0, (size_t)Mz*512*2, stream);
    hipMemsetAsync(ec, 0, (size_t)Mz*256*4, stream);
    hipMemsetAsync(outbuf, 0, (size_t)NSTEP*Mz*4, stream);

    prep3<<<6912, 256, 0, stream>>>(encWq, encWk, encWv, encWg,
                                    decWq, decWk, decWv, decWg, embW,
                                    Pqkv_e, Pqkv_d, Pemb, Pg_e, Pg_d);

    for (int k = 0; k <= NSTEP; ++k) {
        __bf16* P = (k & 1) ? Xb : Xa;
        __bf16* Q = (k & 1) ? Xa : Xb;
        step_k<<<512, 512, 0, stream>>>(k, input, P, Q,
                                        Pqkv_e, Pqkv_d, Pemb, Pg_e, Pg_d,
                                        encWg, encbg, decbg, embb, outW,
                                        ec, outbuf);
    }
    assemble_k<<<(Bz*(NSTEP-TPz)*Sz + 255)/256, 256, 0, stream>>>(
        outbuf, input, outb, (float*)d_out);
}